// Round 1
// baseline (847.025 us; speedup 1.0000x reference)
//
#include <hip/hip_runtime.h>

typedef __bf16 bf16;
typedef __bf16 bf16x8 __attribute__((ext_vector_type(8)));
typedef float f32x4 __attribute__((ext_vector_type(4)));

#define DEVFN static __device__ __forceinline__

constexpr int S = 2048, Hdim = 2048, NH = 16, NKV = 4, HD = 128, RHD = 64, QC = 1536, KVC = 512;
constexpr int QKD = HD + RHD;                 // 192
constexpr float RMS_EPS = 1e-6f;
constexpr float ATT_SCALE = 0.07216878364870323f;  // 1/sqrt(192)

// ---------------- reductions ----------------
DEVFN float wave_sum(float v) {
#pragma unroll
  for (int o = 32; o > 0; o >>= 1) v += __shfl_xor(v, o, 64);
  return v;
}
DEVFN float wave_max(float v) {
#pragma unroll
  for (int o = 32; o > 0; o >>= 1) v = fmaxf(v, __shfl_xor(v, o, 64));
  return v;
}
DEVFN float block_sum(float v) {
  __shared__ float red_s[4];
  v = wave_sum(v);
  int lane = threadIdx.x & 63, wid = threadIdx.x >> 6;
  if (lane == 0) red_s[wid] = v;
  __syncthreads();
  v = red_s[0] + red_s[1] + red_s[2] + red_s[3];
  __syncthreads();
  return v;
}
DEVFN float block_max(float v) {
  __shared__ float red_m[4];
  v = wave_max(v);
  int lane = threadIdx.x & 63, wid = threadIdx.x >> 6;
  if (lane == 0) red_m[wid] = v;
  __syncthreads();
  v = fmaxf(fmaxf(red_m[0], red_m[1]), fmaxf(red_m[2], red_m[3]));
  __syncthreads();
  return v;
}

// ---------------- GEMM core: C[M,N] = A[M,K] * Bt[N,K]^T ----------------
// 128x128 tile, 4 waves (2x2), each wave 64x64 = 4x4 fragments of 16x16, BK=32.
// LDS padded to stride 40 elems (80B) -> <=2-way bank aliasing on ds_read_b128.
template <typename T>
DEVFN void stage8(bf16* __restrict__ lds, const T* __restrict__ G, int grow, int gcol,
                  int ld, int RMAX, int lrow, int lcol) {
  bf16x8 v;
  if (grow < RMAX) {
    if constexpr (sizeof(T) == 2) {
      v = *reinterpret_cast<const bf16x8*>(G + (size_t)grow * ld + gcol);
    } else {
      const float* p = reinterpret_cast<const float*>(G) + (size_t)grow * ld + gcol;
      float4 f0 = *reinterpret_cast<const float4*>(p);
      float4 f1 = *reinterpret_cast<const float4*>(p + 4);
      v[0] = (bf16)f0.x; v[1] = (bf16)f0.y; v[2] = (bf16)f0.z; v[3] = (bf16)f0.w;
      v[4] = (bf16)f1.x; v[5] = (bf16)f1.y; v[6] = (bf16)f1.z; v[7] = (bf16)f1.w;
    }
  } else {
#pragma unroll
    for (int z = 0; z < 8; z++) v[z] = (bf16)0.f;
  }
  *reinterpret_cast<bf16x8*>(&lds[lrow * 40 + lcol]) = v;
}

template <typename AT, typename OT>
DEVFN void gemm_tile(const AT* __restrict__ A, const bf16* __restrict__ Bt, OT* __restrict__ C,
                     int M, int N, int K, int lda, int ldb, int ldc, int m0, int n0, float scale) {
  __shared__ alignas(16) bf16 As[128 * 40];
  __shared__ alignas(16) bf16 Bs[128 * 40];
  const int t = threadIdx.x;
  const int lane = t & 63;
  const int wm = ((t >> 7) & 1) * 64;   // wave row
  const int wn = ((t >> 6) & 1) * 64;   // wave col
  const int lr = lane & 15;
  const int lk = (lane >> 4) * 8;
  const int r0 = t >> 2;                // staging row 0..63 (and +64)
  const int c0 = (t & 3) * 8;           // staging col {0,8,16,24}
  f32x4 acc[4][4];
#pragma unroll
  for (int i = 0; i < 4; i++)
#pragma unroll
    for (int j = 0; j < 4; j++) { f32x4 z = {0.f, 0.f, 0.f, 0.f}; acc[i][j] = z; }

  for (int kk = 0; kk < K; kk += 32) {
    stage8(As, A, m0 + r0, kk + c0, lda, M, r0, c0);
    stage8(As, A, m0 + r0 + 64, kk + c0, lda, M, r0 + 64, c0);
    stage8(Bs, Bt, n0 + r0, kk + c0, ldb, N, r0, c0);
    stage8(Bs, Bt, n0 + r0 + 64, kk + c0, ldb, N, r0 + 64, c0);
    __syncthreads();
    bf16x8 a[4], b[4];
#pragma unroll
    for (int i = 0; i < 4; i++)
      a[i] = *reinterpret_cast<const bf16x8*>(&As[(wm + i * 16 + lr) * 40 + lk]);
#pragma unroll
    for (int i = 0; i < 4; i++)
      b[i] = *reinterpret_cast<const bf16x8*>(&Bs[(wn + i * 16 + lr) * 40 + lk]);
#pragma unroll
    for (int i = 0; i < 4; i++)
#pragma unroll
      for (int j = 0; j < 4; j++)
        acc[i][j] = __builtin_amdgcn_mfma_f32_16x16x32_bf16(a[i], b[j], acc[i][j], 0, 0, 0);
    __syncthreads();
  }
  // C/D layout: col = lane&15, row = (lane>>4)*4 + q  [m89 verified]
  const int orow = (lane >> 4) * 4;
#pragma unroll
  for (int i = 0; i < 4; i++) {
#pragma unroll
    for (int j = 0; j < 4; j++) {
      int col = n0 + wn + j * 16 + lr;
      if (col < N) {
#pragma unroll
        for (int q = 0; q < 4; q++) {
          int row = m0 + wm + i * 16 + orow + q;
          if (row < M) C[(size_t)row * ldc + col] = (OT)(acc[i][j][q] * scale);
        }
      }
    }
  }
}

template <typename AT, typename OT>
__global__ __launch_bounds__(256) void gemm_nt(const AT* __restrict__ A, const bf16* __restrict__ Bt,
                                               OT* __restrict__ C, int M, int N, int K, int lda,
                                               int ldb, int ldc, float scale) {
  gemm_tile<AT, OT>(A, Bt, C, M, N, K, lda, ldb, ldc, blockIdx.y * 128, blockIdx.x * 128, scale);
}

__global__ __launch_bounds__(256) void gemm_scores(const bf16* __restrict__ qpack,
                                                   const bf16* __restrict__ kpack,
                                                   float* __restrict__ attn) {
  int h = blockIdx.z;
  int m0 = blockIdx.y * 128, n0 = blockIdx.x * 128;
  if (n0 > m0) return;  // fully-masked causal block
  gemm_tile<bf16, float>(qpack + (size_t)h * S * QKD, kpack + (size_t)(h >> 2) * S * QKD,
                         attn + (size_t)h * S * S, S, S, QKD, QKD, QKD, S, m0, n0, ATT_SCALE);
}

__global__ __launch_bounds__(256) void gemm_pv(const float* __restrict__ attn,
                                               const bf16* __restrict__ vt,
                                               bf16* __restrict__ ctxb) {
  int h = blockIdx.z;
  gemm_tile<float, bf16>(attn + (size_t)h * S * S, vt + (size_t)(h >> 2) * HD * S, ctxb + h * HD,
                         S, HD, S, S, S, Hdim, blockIdx.y * 128, 0, 1.0f);
}

// ---------------- elementwise / reshape kernels ----------------
__global__ __launch_bounds__(256) void cast_f32_bf16(const float* __restrict__ in,
                                                     bf16* __restrict__ out, int n8) {
  int i = blockIdx.x * 256 + threadIdx.x;
  if (i >= n8) return;
  float4 f0 = *reinterpret_cast<const float4*>(in + (size_t)i * 8);
  float4 f1 = *reinterpret_cast<const float4*>(in + (size_t)i * 8 + 4);
  bf16x8 v;
  v[0] = (bf16)f0.x; v[1] = (bf16)f0.y; v[2] = (bf16)f0.z; v[3] = (bf16)f0.w;
  v[4] = (bf16)f1.x; v[5] = (bf16)f1.y; v[6] = (bf16)f1.z; v[7] = (bf16)f1.w;
  *reinterpret_cast<bf16x8*>(out + (size_t)i * 8) = v;
}

// in [R][C] (fp32 or bf16) -> out [C][R] bf16
template <typename IT>
__global__ __launch_bounds__(256) void transpose_cast(const IT* __restrict__ in,
                                                      bf16* __restrict__ out, int R, int C) {
  __shared__ float tile[32][33];
  int tx = threadIdx.x, ty = threadIdx.y;
  int cb = blockIdx.x * 32, rb = blockIdx.y * 32;
#pragma unroll
  for (int j = 0; j < 32; j += 8) {
    int r = rb + ty + j, c = cb + tx;
    tile[ty + j][tx] = (r < R && c < C) ? (float)in[(size_t)r * C + c] : 0.f;
  }
  __syncthreads();
#pragma unroll
  for (int j = 0; j < 32; j += 8) {
    int oc = rb + tx;          // R-dim (output col)
    int orw = cb + ty + j;     // C-dim (output row)
    if (orw < C && oc < R) out[(size_t)orw * R + oc] = (bf16)tile[tx][ty + j];
  }
}

__global__ __launch_bounds__(256) void rmsnorm_k(const float* __restrict__ in,
                                                 const float* __restrict__ w,
                                                 bf16* __restrict__ out, int C) {
  int row = blockIdx.x;
  const float* p = in + (size_t)row * C;
  float s = 0.f;
  for (int i = threadIdx.x; i < C; i += 256) { float v = p[i]; s += v * v; }
  s = block_sum(s);
  float r = rsqrtf(s / (float)C + RMS_EPS);
  for (int i = threadIdx.x; i < C; i += 256) out[(size_t)row * C + i] = (bf16)(p[i] * r * w[i]);
}

// qpack[h][s][0:128] = qcb[s][h*128+d]
__global__ __launch_bounds__(256) void pack_qc(const bf16* __restrict__ qcb,
                                               bf16* __restrict__ qpack) {
  int i = blockIdx.x * 256 + threadIdx.x;  // chunk of 8
  if (i >= NH * S * (HD / 8)) return;
  int d8 = i & 15, s = (i >> 4) & 2047, h = i >> 15;
  const int4 v = *reinterpret_cast<const int4*>(qcb + (size_t)s * Hdim + h * HD + d8 * 8);
  *reinterpret_cast<int4*>(qpack + ((size_t)h * S + s) * QKD + d8 * 8) = v;
}

// kpack[g][s][0:128] = kcb[s][g*128+d]
__global__ __launch_bounds__(256) void pack_kc(const bf16* __restrict__ kcb,
                                               bf16* __restrict__ kpack) {
  int i = blockIdx.x * 256 + threadIdx.x;
  if (i >= NKV * S * (HD / 8)) return;
  int d8 = i & 15, s = (i >> 4) & 2047, g = i >> 15;
  const int4 v = *reinterpret_cast<const int4*>(kcb + (size_t)s * (NKV * HD) + g * HD + d8 * 8);
  *reinterpret_cast<int4*>(kpack + ((size_t)g * S + s) * QKD + d8 * 8) = v;
}

// qpack[h][s][128+d] = rope(qr_raw[s][h*64+d])
__global__ __launch_bounds__(256) void rope_q_kernel(const bf16* __restrict__ qr_raw,
                                                     const float* __restrict__ cosp,
                                                     const float* __restrict__ sinp,
                                                     bf16* __restrict__ qpack) {
  int i = blockIdx.x * 256 + threadIdx.x;
  if (i >= NH * S * RHD) return;
  int d = i & 63, s = (i >> 6) & 2047, h = i >> 17;
  const bf16* x = qr_raw + (size_t)s * (NH * RHD) + h * RHD;
  float c = cosp[s * RHD + d], sn = sinp[s * RHD + d];
  float xv = (float)x[d];
  float xo = (d < 32) ? -(float)x[d + 32] : (float)x[d - 32];
  qpack[((size_t)h * S + s) * QKD + HD + d] = (bf16)(xv * c + xo * sn);
}

// kpack[g][s][128+d] = rope(kr_raw[s][d]) for all g
__global__ __launch_bounds__(256) void rope_k_kernel(const bf16* __restrict__ kr_raw,
                                                     const float* __restrict__ cosp,
                                                     const float* __restrict__ sinp,
                                                     bf16* __restrict__ kpack) {
  int i = blockIdx.x * 256 + threadIdx.x;
  if (i >= S * RHD) return;
  int d = i & 63, s = i >> 6;
  float c = cosp[s * RHD + d], sn = sinp[s * RHD + d];
  float xv = (float)kr_raw[(size_t)s * RHD + d];
  float xo = (d < 32) ? -(float)kr_raw[(size_t)s * RHD + d + 32]
                      : (float)kr_raw[(size_t)s * RHD + d - 32];
  float val = xv * c + xo * sn;
#pragma unroll
  for (int g = 0; g < NKV; g++) kpack[((size_t)g * S + s) * QKD + HD + d] = (bf16)val;
}

// in-place causal softmax on attn rows; zeros the masked tail
__global__ __launch_bounds__(256) void softmax_rows(float* __restrict__ attn) {
  int s = blockIdx.x, h = blockIdx.y;
  float* row = attn + ((size_t)h * S + s) * S;
  __shared__ float buf[S];
  int n = s + 1;
  float m = -1e30f;
  for (int i = threadIdx.x; i < n; i += 256) { float v = row[i]; buf[i] = v; m = fmaxf(m, v); }
  m = block_max(m);
  float sum = 0.f;
  for (int i = threadIdx.x; i < n; i += 256) { float e = __expf(buf[i] - m); buf[i] = e; sum += e; }
  sum = block_sum(sum);
  float inv = 1.0f / sum;
  for (int i = threadIdx.x; i < n; i += 256) row[i] = buf[i] * inv;
  for (int i = n + threadIdx.x; i < S; i += 256) row[i] = 0.f;
}

// ---------------- launcher ----------------
extern "C" void kernel_launch(void* const* d_in, const int* in_sizes, int n_in, void* d_out,
                              int out_size, void* d_ws, size_t ws_size, hipStream_t stream) {
  const float* Xf = (const float*)d_in[0];
  const float* cosp = (const float*)d_in[1];
  const float* sinp = (const float*)d_in[2];
  // d_in[3] = mask (tril, implied by causal handling)
  const float* w_down_q = (const float*)d_in[4];
  const float* w_up_q = (const float*)d_in[5];
  const float* w_qr = (const float*)d_in[6];
  const float* w_down_kv = (const float*)d_in[7];
  const float* w_up_k = (const float*)d_in[8];
  const float* w_up_v = (const float*)d_in[9];
  const float* w_kr = (const float*)d_in[10];
  const float* w_o = (const float*)d_in[11];
  const float* q_norm_w = (const float*)d_in[12];
  const float* k_norm_w = (const float*)d_in[13];

  float* out0 = (float*)d_out;                    // (S, H) fp32
  float* attn = out0 + (size_t)S * Hdim;          // (NH, S, S) fp32

  char* base = (char*)d_ws;
  size_t off = 0;
  auto carve = [&](size_t bytes) -> void* {
    void* p = base + off;
    off += (bytes + 255) & ~(size_t)255;
    return p;
  };
  bf16* Xb     = (bf16*)carve((size_t)S * Hdim * 2);
  bf16* wt_dq  = (bf16*)carve((size_t)QC * Hdim * 2);      // [QC][H]
  bf16* wt_uq  = (bf16*)carve((size_t)Hdim * QC * 2);      // [H][QC]
  bf16* wt_qr  = (bf16*)carve((size_t)NH * RHD * QC * 2);  // [1024][QC]
  bf16* wt_dkv = (bf16*)carve((size_t)KVC * Hdim * 2);     // [KVC][H]
  bf16* wt_uk  = (bf16*)carve((size_t)NKV * HD * KVC * 2); // [512][KVC]
  bf16* wt_uv  = (bf16*)carve((size_t)NKV * HD * KVC * 2);
  bf16* wt_kr  = (bf16*)carve((size_t)RHD * Hdim * 2);     // [64][H]
  bf16* wt_o   = (bf16*)carve((size_t)Hdim * Hdim * 2);    // [H][H]
  float* cqp   = (float*)carve((size_t)S * QC * 4);
  float* ckvp  = (float*)carve((size_t)S * KVC * 4);
  bf16* cqb    = (bf16*)carve((size_t)S * QC * 2);
  bf16* ckvb   = (bf16*)carve((size_t)S * KVC * 2);
  bf16* qcb    = (bf16*)carve((size_t)S * Hdim * 2);
  bf16* qr_raw = (bf16*)carve((size_t)S * NH * RHD * 2);
  bf16* kr_raw = (bf16*)carve((size_t)S * RHD * 2);
  bf16* kcb    = (bf16*)carve((size_t)S * NKV * HD * 2);
  bf16* vb     = (bf16*)carve((size_t)S * NKV * HD * 2);
  bf16* qpack  = (bf16*)carve((size_t)NH * S * QKD * 2);   // [h][s][192]
  bf16* kpack  = (bf16*)carve((size_t)NKV * S * QKD * 2);  // [g][s][192]
  bf16* vt     = (bf16*)carve((size_t)NKV * HD * S * 2);   // [g*128+d][s]
  bf16* ctxb   = (bf16*)carve((size_t)S * Hdim * 2);       // [s][h*128+d]
  (void)in_sizes; (void)n_in; (void)out_size; (void)ws_size;

  dim3 tb(32, 8);
  // casts + weight transposes
  cast_f32_bf16<<<(S * Hdim / 8 + 255) / 256, 256, 0, stream>>>(Xf, Xb, S * Hdim / 8);
  transpose_cast<float><<<dim3(QC / 32, Hdim / 32), tb, 0, stream>>>(w_down_q, wt_dq, Hdim, QC);
  transpose_cast<float><<<dim3(Hdim / 32, QC / 32), tb, 0, stream>>>(w_up_q, wt_uq, QC, Hdim);
  transpose_cast<float><<<dim3(NH * RHD / 32, QC / 32), tb, 0, stream>>>(w_qr, wt_qr, QC, NH * RHD);
  transpose_cast<float><<<dim3(KVC / 32, Hdim / 32), tb, 0, stream>>>(w_down_kv, wt_dkv, Hdim, KVC);
  transpose_cast<float><<<dim3(NKV * HD / 32, KVC / 32), tb, 0, stream>>>(w_up_k, wt_uk, KVC, NKV * HD);
  transpose_cast<float><<<dim3(NKV * HD / 32, KVC / 32), tb, 0, stream>>>(w_up_v, wt_uv, KVC, NKV * HD);
  transpose_cast<float><<<dim3(RHD / 32, Hdim / 32), tb, 0, stream>>>(w_kr, wt_kr, Hdim, RHD);
  transpose_cast<float><<<dim3(Hdim / 32, Hdim / 32), tb, 0, stream>>>(w_o, wt_o, Hdim, Hdim);

  // down projections + RMSNorm
  gemm_nt<bf16, float><<<dim3(QC / 128, S / 128), 256, 0, stream>>>(Xb, wt_dq, cqp, S, QC, Hdim, Hdim, Hdim, QC, 1.f);
  gemm_nt<bf16, float><<<dim3(KVC / 128, S / 128), 256, 0, stream>>>(Xb, wt_dkv, ckvp, S, KVC, Hdim, Hdim, Hdim, KVC, 1.f);
  rmsnorm_k<<<S, 256, 0, stream>>>(cqp, q_norm_w, cqb, QC);
  rmsnorm_k<<<S, 256, 0, stream>>>(ckvp, k_norm_w, ckvb, KVC);

  // up projections
  gemm_nt<bf16, bf16><<<dim3(Hdim / 128, S / 128), 256, 0, stream>>>(cqb, wt_uq, qcb, S, Hdim, QC, QC, QC, Hdim, 1.f);
  gemm_nt<bf16, bf16><<<dim3(NH * RHD / 128, S / 128), 256, 0, stream>>>(cqb, wt_qr, qr_raw, S, NH * RHD, QC, QC, QC, NH * RHD, 1.f);
  gemm_nt<bf16, bf16><<<dim3(1, S / 128), 256, 0, stream>>>(Xb, wt_kr, kr_raw, S, RHD, Hdim, Hdim, Hdim, RHD, 1.f);
  gemm_nt<bf16, bf16><<<dim3(NKV * HD / 128, S / 128), 256, 0, stream>>>(ckvb, wt_uk, kcb, S, NKV * HD, KVC, KVC, KVC, NKV * HD, 1.f);
  gemm_nt<bf16, bf16><<<dim3(NKV * HD / 128, S / 128), 256, 0, stream>>>(ckvb, wt_uv, vb, S, NKV * HD, KVC, KVC, KVC, NKV * HD, 1.f);

  // pack heads + RoPE + V transpose
  pack_qc<<<NH * S * (HD / 8) / 256, 256, 0, stream>>>(qcb, qpack);
  pack_kc<<<NKV * S * (HD / 8) / 256, 256, 0, stream>>>(kcb, kpack);
  rope_q_kernel<<<NH * S * RHD / 256, 256, 0, stream>>>(qr_raw, cosp, sinp, qpack);
  rope_k_kernel<<<S * RHD / 256, 256, 0, stream>>>(kr_raw, cosp, sinp, kpack);
  transpose_cast<bf16><<<dim3(NKV * HD / 32, S / 32), tb, 0, stream>>>(vb, vt, S, NKV * HD);

  // scores -> softmax (in-place, into d_out attn region) -> PV -> out proj
  gemm_scores<<<dim3(S / 128, S / 128, NH), 256, 0, stream>>>(qpack, kpack, attn);
  softmax_rows<<<dim3(S, NH), 256, 0, stream>>>(attn);
  gemm_pv<<<dim3(1, S / 128, NH), 256, 0, stream>>>(attn, vt, ctxb);
  gemm_nt<bf16, float><<<dim3(Hdim / 128, S / 128), 256, 0, stream>>>(ctxb, wt_o, out0, S, Hdim, Hdim, Hdim, Hdim, Hdim, 1.f);
}

// Round 2
// 594.572 us; speedup vs baseline: 1.4246x; 1.4246x over previous
//
#include <hip/hip_runtime.h>

typedef __bf16 bf16;
typedef __bf16 bf16x8 __attribute__((ext_vector_type(8)));
typedef float f32x4 __attribute__((ext_vector_type(4)));

#define DEVFN static __device__ __forceinline__

constexpr int S = 2048, Hdim = 2048, NH = 16, NKV = 4, HD = 128, RHD = 64, QC = 1536, KVC = 512;
constexpr int QKD = HD + RHD;                 // 192
constexpr float RMS_EPS = 1e-6f;
constexpr float ATT_SCALE = 0.07216878364870323f;  // 1/sqrt(192)

// ---------------- reductions ----------------
DEVFN float wave_sum(float v) {
#pragma unroll
  for (int o = 32; o > 0; o >>= 1) v += __shfl_xor(v, o, 64);
  return v;
}
DEVFN float wave_max(float v) {
#pragma unroll
  for (int o = 32; o > 0; o >>= 1) v = fmaxf(v, __shfl_xor(v, o, 64));
  return v;
}
DEVFN float block_sum(float v) {
  __shared__ float red_s[4];
  v = wave_sum(v);
  int lane = threadIdx.x & 63, wid = threadIdx.x >> 6;
  if (lane == 0) red_s[wid] = v;
  __syncthreads();
  v = red_s[0] + red_s[1] + red_s[2] + red_s[3];
  __syncthreads();
  return v;
}
DEVFN float block_max(float v) {
  __shared__ float red_m[4];
  v = wave_max(v);
  int lane = threadIdx.x & 63, wid = threadIdx.x >> 6;
  if (lane == 0) red_m[wid] = v;
  __syncthreads();
  v = fmaxf(fmaxf(red_m[0], red_m[1]), fmaxf(red_m[2], red_m[3]));
  __syncthreads();
  return v;
}

// ---------------- async global->LDS (16B per lane) ----------------
DEVFN void gload16(const bf16* g, bf16* l) {
  __builtin_amdgcn_global_load_lds(
      (const __attribute__((address_space(1))) uint32_t*)g,
      (__attribute__((address_space(3))) uint32_t*)l, 16, 0, 0);
}

// ---------------- async GEMM core (m97 structure): C = A[M,K] * Bt[N,K]^T ---
// 128x128 tile, BK=32, 4 waves 2x2, linear LDS [128][32], global_load_lds x16.
template <typename OT>
DEVFN void gemm_core_async(const bf16* __restrict__ A, const bf16* __restrict__ Bt,
                           OT* __restrict__ C, int N, int lda, int ldb, int ldc,
                           int m0, int n0, float scale, int kend) {
  __shared__ alignas(16) bf16 As[128 * 32];
  __shared__ alignas(16) bf16 Bs[128 * 32];
  const int t = threadIdx.x;
  const int lane = t & 63;
  const int wm = ((t >> 7) & 1) * 64;
  const int wn = ((t >> 6) & 1) * 64;
  const int lr = lane & 15;
  const int lk = (lane >> 4) * 8;
  // staging: chunk c = issue*256+t -> row c>>2, col (c&3)*8; LDS byte off = c*16
  const int srow = t >> 2;
  const int scol = (t & 3) * 8;
  const bf16* Ab = A + (size_t)(m0 + srow) * lda + scol;
  const bf16* Bb = Bt + (size_t)(n0 + srow) * ldb + scol;
  bf16* Al = As + t * 8;
  bf16* Bl = Bs + t * 8;

  f32x4 acc[4][4];
#pragma unroll
  for (int i = 0; i < 4; i++)
#pragma unroll
    for (int j = 0; j < 4; j++) { f32x4 z = {0.f, 0.f, 0.f, 0.f}; acc[i][j] = z; }

  for (int kk = 0; kk < kend; kk += 32) {
    gload16(Ab + kk, Al);
    gload16(Ab + (size_t)64 * lda + kk, Al + 2048);
    gload16(Bb + kk, Bl);
    gload16(Bb + (size_t)64 * ldb + kk, Bl + 2048);
    __syncthreads();
    bf16x8 a[4], b[4];
#pragma unroll
    for (int i = 0; i < 4; i++)
      a[i] = *reinterpret_cast<const bf16x8*>(&As[(wm + i * 16 + lr) * 32 + lk]);
#pragma unroll
    for (int i = 0; i < 4; i++)
      b[i] = *reinterpret_cast<const bf16x8*>(&Bs[(wn + i * 16 + lr) * 32 + lk]);
#pragma unroll
    for (int i = 0; i < 4; i++)
#pragma unroll
      for (int j = 0; j < 4; j++)
        acc[i][j] = __builtin_amdgcn_mfma_f32_16x16x32_bf16(a[i], b[j], acc[i][j], 0, 0, 0);
    __syncthreads();
  }
  // C/D layout: col = lane&15, row = (lane>>4)*4 + q
  const int orow = (lane >> 4) * 4;
#pragma unroll
  for (int i = 0; i < 4; i++) {
#pragma unroll
    for (int j = 0; j < 4; j++) {
      int col = n0 + wn + j * 16 + lr;
      if (col < N) {
#pragma unroll
        for (int q = 0; q < 4; q++) {
          int row = m0 + wm + i * 16 + orow + q;
          C[(size_t)row * ldc + col] = (OT)(acc[i][j][q] * scale);
        }
      }
    }
  }
}

template <typename OT>
__global__ __launch_bounds__(256) void gemm_nt(const bf16* __restrict__ A, const bf16* __restrict__ Bt,
                                               OT* __restrict__ C, int N, int K, int lda,
                                               int ldb, int ldc, float scale) {
  gemm_core_async<OT>(A, Bt, C, N, lda, ldb, ldc, blockIdx.y * 128, blockIdx.x * 128, scale, K);
}

// scores for one KV group (4 heads), causal block-skip
__global__ __launch_bounds__(256) void gemm_scores(const bf16* __restrict__ qpack,
                                                   const bf16* __restrict__ kpack,
                                                   float* __restrict__ attn, int g) {
  int h = g * 4 + blockIdx.z;
  int m0 = blockIdx.y * 128, n0 = blockIdx.x * 128;
  if (n0 > m0) return;  // fully-masked causal block
  gemm_core_async<float>(qpack + (size_t)h * S * QKD, kpack + (size_t)g * S * QKD,
                         attn + (size_t)h * S * S, S, QKD, QKD, S, m0, n0, ATT_SCALE, QKD);
}

// ---------------- reg-staged GEMM core (fp32 A) for PV ----------------
DEVFN void stage8f(bf16* __restrict__ lds, const float* __restrict__ G, int grow, int gcol,
                   int ld, int lrow, int lcol) {
  const float* p = G + (size_t)grow * ld + gcol;
  float4 f0 = *reinterpret_cast<const float4*>(p);
  float4 f1 = *reinterpret_cast<const float4*>(p + 4);
  bf16x8 v;
  v[0] = (bf16)f0.x; v[1] = (bf16)f0.y; v[2] = (bf16)f0.z; v[3] = (bf16)f0.w;
  v[4] = (bf16)f1.x; v[5] = (bf16)f1.y; v[6] = (bf16)f1.z; v[7] = (bf16)f1.w;
  *reinterpret_cast<bf16x8*>(&lds[lrow * 40 + lcol]) = v;
}
DEVFN void stage8b(bf16* __restrict__ lds, const bf16* __restrict__ G, int grow, int gcol,
                   int ld, int lrow, int lcol) {
  *reinterpret_cast<bf16x8*>(&lds[lrow * 40 + lcol]) =
      *reinterpret_cast<const bf16x8*>(G + (size_t)grow * ld + gcol);
}

// PV: ctx[m, d] = sum_k attn[m,k] * vt[d,k], causal (k < m0+128)
__global__ __launch_bounds__(256) void gemm_pv(const float* __restrict__ attn,
                                               const bf16* __restrict__ vt,
                                               bf16* __restrict__ ctxb) {
  int h = blockIdx.z;
  const float* A = attn + (size_t)h * S * S;
  const bf16* Bt = vt + (size_t)(h >> 2) * HD * S;
  bf16* C = ctxb + h * HD;
  const int m0 = blockIdx.y * 128;
  const int kend = m0 + 128;  // causal
  __shared__ alignas(16) bf16 As[128 * 40];
  __shared__ alignas(16) bf16 Bs[128 * 40];
  const int t = threadIdx.x;
  const int lane = t & 63;
  const int wm = ((t >> 7) & 1) * 64;
  const int wn = ((t >> 6) & 1) * 64;
  const int lr = lane & 15;
  const int lk = (lane >> 4) * 8;
  const int r0 = t >> 2;
  const int c0 = (t & 3) * 8;
  f32x4 acc[4][4];
#pragma unroll
  for (int i = 0; i < 4; i++)
#pragma unroll
    for (int j = 0; j < 4; j++) { f32x4 z = {0.f, 0.f, 0.f, 0.f}; acc[i][j] = z; }

  for (int kk = 0; kk < kend; kk += 32) {
    stage8f(As, A, m0 + r0, kk + c0, S, r0, c0);
    stage8f(As, A, m0 + r0 + 64, kk + c0, S, r0 + 64, c0);
    stage8b(Bs, Bt, r0, kk + c0, S, r0, c0);
    stage8b(Bs, Bt, r0 + 64, kk + c0, S, r0 + 64, c0);
    __syncthreads();
    bf16x8 a[4], b[4];
#pragma unroll
    for (int i = 0; i < 4; i++)
      a[i] = *reinterpret_cast<const bf16x8*>(&As[(wm + i * 16 + lr) * 40 + lk]);
#pragma unroll
    for (int i = 0; i < 4; i++)
      b[i] = *reinterpret_cast<const bf16x8*>(&Bs[(wn + i * 16 + lr) * 40 + lk]);
#pragma unroll
    for (int i = 0; i < 4; i++)
#pragma unroll
      for (int j = 0; j < 4; j++)
        acc[i][j] = __builtin_amdgcn_mfma_f32_16x16x32_bf16(a[i], b[j], acc[i][j], 0, 0, 0);
    __syncthreads();
  }
  const int orow = (lane >> 4) * 4;
#pragma unroll
  for (int i = 0; i < 4; i++) {
#pragma unroll
    for (int j = 0; j < 4; j++) {
      int col = wn + j * 16 + lr;  // HD = 128 exactly
#pragma unroll
      for (int q = 0; q < 4; q++) {
        int row = m0 + wm + i * 16 + orow + q;
        C[(size_t)row * Hdim + col] = (bf16)acc[i][j][q];
      }
    }
  }
}

// ---------------- elementwise / reshape kernels ----------------
__global__ __launch_bounds__(256) void cast_f32_bf16(const float* __restrict__ in,
                                                     bf16* __restrict__ out, int n8) {
  int i = blockIdx.x * 256 + threadIdx.x;
  if (i >= n8) return;
  float4 f0 = *reinterpret_cast<const float4*>(in + (size_t)i * 8);
  float4 f1 = *reinterpret_cast<const float4*>(in + (size_t)i * 8 + 4);
  bf16x8 v;
  v[0] = (bf16)f0.x; v[1] = (bf16)f0.y; v[2] = (bf16)f0.z; v[3] = (bf16)f0.w;
  v[4] = (bf16)f1.x; v[5] = (bf16)f1.y; v[6] = (bf16)f1.z; v[7] = (bf16)f1.w;
  *reinterpret_cast<bf16x8*>(out + (size_t)i * 8) = v;
}

// in [R][C] (fp32 or bf16) -> out [C][R] bf16
template <typename IT>
__global__ __launch_bounds__(256) void transpose_cast(const IT* __restrict__ in,
                                                      bf16* __restrict__ out, int R, int C) {
  __shared__ float tile[32][33];
  int tx = threadIdx.x, ty = threadIdx.y;
  int cb = blockIdx.x * 32, rb = blockIdx.y * 32;
#pragma unroll
  for (int j = 0; j < 32; j += 8) {
    int r = rb + ty + j, c = cb + tx;
    tile[ty + j][tx] = (r < R && c < C) ? (float)in[(size_t)r * C + c] : 0.f;
  }
  __syncthreads();
#pragma unroll
  for (int j = 0; j < 32; j += 8) {
    int oc = rb + tx;
    int orw = cb + ty + j;
    if (orw < C && oc < R) out[(size_t)orw * R + oc] = (bf16)tile[tx][ty + j];
  }
}

__global__ __launch_bounds__(256) void rmsnorm_k(const float* __restrict__ in,
                                                 const float* __restrict__ w,
                                                 bf16* __restrict__ out, int C) {
  int row = blockIdx.x;
  const float* p = in + (size_t)row * C;
  float s = 0.f;
  for (int i = threadIdx.x; i < C; i += 256) { float v = p[i]; s += v * v; }
  s = block_sum(s);
  float r = rsqrtf(s / (float)C + RMS_EPS);
  for (int i = threadIdx.x; i < C; i += 256) out[(size_t)row * C + i] = (bf16)(p[i] * r * w[i]);
}

__global__ __launch_bounds__(256) void pack_qc(const bf16* __restrict__ qcb,
                                               bf16* __restrict__ qpack) {
  int i = blockIdx.x * 256 + threadIdx.x;
  if (i >= NH * S * (HD / 8)) return;
  int d8 = i & 15, s = (i >> 4) & 2047, h = i >> 15;
  const int4 v = *reinterpret_cast<const int4*>(qcb + (size_t)s * Hdim + h * HD + d8 * 8);
  *reinterpret_cast<int4*>(qpack + ((size_t)h * S + s) * QKD + d8 * 8) = v;
}

__global__ __launch_bounds__(256) void pack_kc(const bf16* __restrict__ kcb,
                                               bf16* __restrict__ kpack) {
  int i = blockIdx.x * 256 + threadIdx.x;
  if (i >= NKV * S * (HD / 8)) return;
  int d8 = i & 15, s = (i >> 4) & 2047, g = i >> 15;
  const int4 v = *reinterpret_cast<const int4*>(kcb + (size_t)s * (NKV * HD) + g * HD + d8 * 8);
  *reinterpret_cast<int4*>(kpack + ((size_t)g * S + s) * QKD + d8 * 8) = v;
}

__global__ __launch_bounds__(256) void rope_q_kernel(const bf16* __restrict__ qr_raw,
                                                     const float* __restrict__ cosp,
                                                     const float* __restrict__ sinp,
                                                     bf16* __restrict__ qpack) {
  int i = blockIdx.x * 256 + threadIdx.x;
  if (i >= NH * S * RHD) return;
  int d = i & 63, s = (i >> 6) & 2047, h = i >> 17;
  const bf16* x = qr_raw + (size_t)s * (NH * RHD) + h * RHD;
  float c = cosp[s * RHD + d], sn = sinp[s * RHD + d];
  float xv = (float)x[d];
  float xo = (d < 32) ? -(float)x[d + 32] : (float)x[d - 32];
  qpack[((size_t)h * S + s) * QKD + HD + d] = (bf16)(xv * c + xo * sn);
}

__global__ __launch_bounds__(256) void rope_k_kernel(const bf16* __restrict__ kr_raw,
                                                     const float* __restrict__ cosp,
                                                     const float* __restrict__ sinp,
                                                     bf16* __restrict__ kpack) {
  int i = blockIdx.x * 256 + threadIdx.x;
  if (i >= S * RHD) return;
  int d = i & 63, s = i >> 6;
  float c = cosp[s * RHD + d], sn = sinp[s * RHD + d];
  float xv = (float)kr_raw[(size_t)s * RHD + d];
  float xo = (d < 32) ? -(float)kr_raw[(size_t)s * RHD + d + 32]
                      : (float)kr_raw[(size_t)s * RHD + d - 32];
  float val = xv * c + xo * sn;
#pragma unroll
  for (int g = 0; g < NKV; g++) kpack[((size_t)g * S + s) * QKD + HD + d] = (bf16)val;
}

// in-place causal softmax; zeros masked tail. h = h0 + blockIdx.y
__global__ __launch_bounds__(256) void softmax_rows(float* __restrict__ attn, int h0) {
  int s = blockIdx.x, h = h0 + blockIdx.y;
  float* row = attn + ((size_t)h * S + s) * S;
  __shared__ float buf[S];
  int n = s + 1;
  float m = -1e30f;
  for (int i = threadIdx.x; i < n; i += 256) { float v = row[i]; buf[i] = v; m = fmaxf(m, v); }
  m = block_max(m);
  float sum = 0.f;
  for (int i = threadIdx.x; i < n; i += 256) { float e = __expf(buf[i] - m); buf[i] = e; sum += e; }
  sum = block_sum(sum);
  float inv = 1.0f / sum;
  for (int i = threadIdx.x; i < n; i += 256) row[i] = buf[i] * inv;
  for (int i = n + threadIdx.x; i < S; i += 256) row[i] = 0.f;
}

// ---------------- launcher ----------------
extern "C" void kernel_launch(void* const* d_in, const int* in_sizes, int n_in, void* d_out,
                              int out_size, void* d_ws, size_t ws_size, hipStream_t stream) {
  const float* Xf = (const float*)d_in[0];
  const float* cosp = (const float*)d_in[1];
  const float* sinp = (const float*)d_in[2];
  const float* w_down_q = (const float*)d_in[4];
  const float* w_up_q = (const float*)d_in[5];
  const float* w_qr = (const float*)d_in[6];
  const float* w_down_kv = (const float*)d_in[7];
  const float* w_up_k = (const float*)d_in[8];
  const float* w_up_v = (const float*)d_in[9];
  const float* w_kr = (const float*)d_in[10];
  const float* w_o = (const float*)d_in[11];
  const float* q_norm_w = (const float*)d_in[12];
  const float* k_norm_w = (const float*)d_in[13];

  float* out0 = (float*)d_out;                    // (S, H) fp32
  float* attn = out0 + (size_t)S * Hdim;          // (NH, S, S) fp32

  char* base = (char*)d_ws;
  size_t off = 0;
  auto carve = [&](size_t bytes) -> void* {
    void* p = base + off;
    off += (bytes + 255) & ~(size_t)255;
    return p;
  };
  bf16* Xb     = (bf16*)carve((size_t)S * Hdim * 2);
  bf16* wt_dq  = (bf16*)carve((size_t)QC * Hdim * 2);
  bf16* wt_uq  = (bf16*)carve((size_t)Hdim * QC * 2);
  bf16* wt_qr  = (bf16*)carve((size_t)NH * RHD * QC * 2);
  bf16* wt_dkv = (bf16*)carve((size_t)KVC * Hdim * 2);
  bf16* wt_uk  = (bf16*)carve((size_t)NKV * HD * KVC * 2);
  bf16* wt_uv  = (bf16*)carve((size_t)NKV * HD * KVC * 2);
  bf16* wt_kr  = (bf16*)carve((size_t)RHD * Hdim * 2);
  bf16* wt_o   = (bf16*)carve((size_t)Hdim * Hdim * 2);
  float* cqp   = (float*)carve((size_t)S * QC * 4);
  float* ckvp  = (float*)carve((size_t)S * KVC * 4);
  bf16* cqb    = (bf16*)carve((size_t)S * QC * 2);
  bf16* ckvb   = (bf16*)carve((size_t)S * KVC * 2);
  bf16* qcb    = (bf16*)carve((size_t)S * Hdim * 2);
  bf16* qr_raw = (bf16*)carve((size_t)S * NH * RHD * 2);
  bf16* kr_raw = (bf16*)carve((size_t)S * RHD * 2);
  bf16* kcb    = (bf16*)carve((size_t)S * NKV * HD * 2);
  bf16* vb     = (bf16*)carve((size_t)S * NKV * HD * 2);
  bf16* qpack  = (bf16*)carve((size_t)NH * S * QKD * 2);
  bf16* kpack  = (bf16*)carve((size_t)NKV * S * QKD * 2);
  bf16* vt     = (bf16*)carve((size_t)NKV * HD * S * 2);
  bf16* ctxb   = (bf16*)carve((size_t)S * Hdim * 2);
  (void)in_sizes; (void)n_in; (void)out_size; (void)ws_size;

  dim3 tb(32, 8);
  cast_f32_bf16<<<(S * Hdim / 8 + 255) / 256, 256, 0, stream>>>(Xf, Xb, S * Hdim / 8);
  transpose_cast<float><<<dim3(QC / 32, Hdim / 32), tb, 0, stream>>>(w_down_q, wt_dq, Hdim, QC);
  transpose_cast<float><<<dim3(Hdim / 32, QC / 32), tb, 0, stream>>>(w_up_q, wt_uq, QC, Hdim);
  transpose_cast<float><<<dim3(NH * RHD / 32, QC / 32), tb, 0, stream>>>(w_qr, wt_qr, QC, NH * RHD);
  transpose_cast<float><<<dim3(KVC / 32, Hdim / 32), tb, 0, stream>>>(w_down_kv, wt_dkv, Hdim, KVC);
  transpose_cast<float><<<dim3(NKV * HD / 32, KVC / 32), tb, 0, stream>>>(w_up_k, wt_uk, KVC, NKV * HD);
  transpose_cast<float><<<dim3(NKV * HD / 32, KVC / 32), tb, 0, stream>>>(w_up_v, wt_uv, KVC, NKV * HD);
  transpose_cast<float><<<dim3(RHD / 32, Hdim / 32), tb, 0, stream>>>(w_kr, wt_kr, Hdim, RHD);
  transpose_cast<float><<<dim3(Hdim / 32, Hdim / 32), tb, 0, stream>>>(w_o, wt_o, Hdim, Hdim);

  // down projections + RMSNorm
  gemm_nt<float><<<dim3(QC / 128, S / 128), 256, 0, stream>>>(Xb, wt_dq, cqp, QC, Hdim, Hdim, Hdim, QC, 1.f);
  gemm_nt<float><<<dim3(KVC / 128, S / 128), 256, 0, stream>>>(Xb, wt_dkv, ckvp, KVC, Hdim, Hdim, Hdim, KVC, 1.f);
  rmsnorm_k<<<S, 256, 0, stream>>>(cqp, q_norm_w, cqb, QC);
  rmsnorm_k<<<S, 256, 0, stream>>>(ckvp, k_norm_w, ckvb, KVC);

  // up projections
  gemm_nt<bf16><<<dim3(Hdim / 128, S / 128), 256, 0, stream>>>(cqb, wt_uq, qcb, Hdim, QC, QC, QC, Hdim, 1.f);
  gemm_nt<bf16><<<dim3(NH * RHD / 128, S / 128), 256, 0, stream>>>(cqb, wt_qr, qr_raw, NH * RHD, QC, QC, QC, NH * RHD, 1.f);
  gemm_nt<bf16><<<dim3(1, S / 128), 256, 0, stream>>>(Xb, wt_kr, kr_raw, RHD, Hdim, Hdim, Hdim, RHD, 1.f);
  gemm_nt<bf16><<<dim3(NKV * HD / 128, S / 128), 256, 0, stream>>>(ckvb, wt_uk, kcb, NKV * HD, KVC, KVC, KVC, NKV * HD, 1.f);
  gemm_nt<bf16><<<dim3(NKV * HD / 128, S / 128), 256, 0, stream>>>(ckvb, wt_uv, vb, NKV * HD, KVC, KVC, KVC, NKV * HD, 1.f);

  // pack heads + RoPE + V transpose
  pack_qc<<<NH * S * (HD / 8) / 256, 256, 0, stream>>>(qcb, qpack);
  pack_kc<<<NKV * S * (HD / 8) / 256, 256, 0, stream>>>(kcb, kpack);
  rope_q_kernel<<<NH * S * RHD / 256, 256, 0, stream>>>(qr_raw, cosp, sinp, qpack);
  rope_k_kernel<<<S * RHD / 256, 256, 0, stream>>>(kr_raw, cosp, sinp, kpack);
  transpose_cast<bf16><<<dim3(NKV * HD / 32, S / 32), tb, 0, stream>>>(vb, vt, S, NKV * HD);

  // scores -> softmax, grouped per KV group for L3 locality
  for (int g = 0; g < NKV; g++) {
    gemm_scores<<<dim3(S / 128, S / 128, 4), 256, 0, stream>>>(qpack, kpack, attn, g);
    softmax_rows<<<dim3(S, 4), 256, 0, stream>>>(attn, g * 4);
  }
  // PV (causal K-limit) + out proj
  gemm_pv<<<dim3(1, S / 128, NH), 256, 0, stream>>>(attn, vt, ctxb);
  gemm_nt<float><<<dim3(Hdim / 128, S / 128), 256, 0, stream>>>(ctxb, wt_o, out0, Hdim, Hdim, Hdim, Hdim, Hdim, 1.f);
}